// Round 4
// baseline (127.138 us; speedup 1.0000x reference)
//
#include <hip/hip_runtime.h>

#define B 2
#define S 2048
#define D 512
#define H 8
#define KD 64

typedef __bf16 bf16_t;
typedef __bf16 bf16x8 __attribute__((ext_vector_type(8)));
typedef __bf16 bf16x4 __attribute__((ext_vector_type(4)));
typedef float f32x4 __attribute__((ext_vector_type(4)));
typedef float f32x16 __attribute__((ext_vector_type(16)));

#define QSCALE 0.1803368801111204f   /* 0.125 * log2(e): exp2-domain softmax */

__device__ __forceinline__ void async_copy16(const void* g, void* l) {
    __builtin_amdgcn_global_load_lds(
        (const __attribute__((address_space(1))) void*)g,
        (__attribute__((address_space(3))) void*)l, 16, 0, 0);
}

// ---------------------------------------------------------------------------
// Kernel 0: weight prep (transpose + f32->bf16, once per launch):
//   Wt{q,k,v}[h][col(64)][d(512)]  <-  W*[h][d][col]
//   WoT[n(512)][k(512)]            <-  Wo[k][n]
// ---------------------------------------------------------------------------
__global__ __launch_bounds__(256) void prep_kernel(
    const float* __restrict__ Wq, const float* __restrict__ Wk,
    const float* __restrict__ Wv, const float* __restrict__ Wo,
    bf16_t* __restrict__ Wtq, bf16_t* __restrict__ Wtk,
    bf16_t* __restrict__ Wtv, bf16_t* __restrict__ WoT)
{
    __shared__ bf16_t tl[64][72];
    const int blk = blockIdx.x, t = threadIdx.x;

    const float* src; bf16_t* dstbase;
    int ld, r0, c0;
    if (blk < 192) {                       // Wq/Wk/Wv
        const int mat = blk >> 6, h = (blk & 63) >> 3, dt = blk & 7;
        const float* W = (mat == 0) ? Wq : (mat == 1) ? Wk : Wv;
        bf16_t* Wt = (mat == 0) ? Wtq : (mat == 1) ? Wtk : Wtv;
        src = W + (size_t)h * D * KD; dstbase = Wt + (size_t)h * KD * D;
        ld = KD; r0 = dt * 64; c0 = 0;
    } else {                               // Wo
        const int kt = (blk - 192) >> 3, nt = (blk - 192) & 7;
        src = Wo; dstbase = WoT;
        ld = D; r0 = kt * 64; c0 = nt * 64;
    }

    { // phase 1: read f32 rows, convert, store to LDS [row][col]
        const int r = t >> 2, cq = (t & 3) * 16;
        const float* sp = src + (size_t)(r0 + r) * ld + c0 + cq;
#pragma unroll
        for (int q = 0; q < 4; ++q) {
            const float4 f = *reinterpret_cast<const float4*>(sp + q * 4);
            tl[r][cq + q * 4 + 0] = (bf16_t)f.x; tl[r][cq + q * 4 + 1] = (bf16_t)f.y;
            tl[r][cq + q * 4 + 2] = (bf16_t)f.z; tl[r][cq + q * 4 + 3] = (bf16_t)f.w;
        }
    }
    __syncthreads();
    { // phase 2: gather transposed, 16B stores
        const int cc = t >> 2, rq = (t & 3) * 16;
        bf16x8 o0, o1;
#pragma unroll
        for (int j = 0; j < 8; ++j) { o0[j] = tl[rq + j][cc]; o1[j] = tl[rq + 8 + j][cc]; }
        bf16_t* dp = dstbase + (size_t)(c0 + cc) * 512 + r0 + rq;
        *reinterpret_cast<bf16x8*>(dp) = o0;
        *reinterpret_cast<bf16x8*>(dp + 8) = o1;
    }
}

// ---------------------------------------------------------------------------
// Kernel 1: fused QKV projection (unchanged from R3 — works).
// ---------------------------------------------------------------------------
__global__ __launch_bounds__(256) void qkv_kernel(
    const float* __restrict__ q_in, const float* __restrict__ k_in, const float* __restrict__ v_in,
    const bf16_t* __restrict__ Wtq, const bf16_t* __restrict__ Wtk, const bf16_t* __restrict__ Wtv,
    const float* __restrict__ bq, const float* __restrict__ bk, const float* __restrict__ bv,
    bf16_t* __restrict__ Qo, bf16_t* __restrict__ Ko, bf16_t* __restrict__ VTo)
{
    __shared__ char wlds[65536];

    const int mat = blockIdx.y;
    const float* Xp     = (mat == 0) ? q_in : (mat == 1) ? k_in : v_in;
    const bf16_t* Wt    = (mat == 0) ? Wtq  : (mat == 1) ? Wtk  : Wtv;
    const float* bias   = (mat == 0) ? bq   : (mat == 1) ? bk   : bv;
    const float scale   = (mat == 0) ? QSCALE : 1.0f;

    const int stile = blockIdx.x & 31;
    const int bh    = blockIdx.x >> 5;
    const int h = bh & (H - 1), b = bh >> 3;

    const int tid = threadIdx.x, wave = tid >> 6, lane = tid & 63;
    const int g = lane >> 4, c = lane & 15;

    // stage Wt[h]: LDS[col][slot] = W[col][slot ^ (col&7)]  (64 x 1KB rows)
    {
        const bf16_t* wbase = Wt + (size_t)h * (64 * 512);
#pragma unroll
        for (int j = 0; j < 16; ++j) {
            const int col = wave * 16 + j;
            const int ss = lane ^ (col & 7);
            async_copy16(wbase + (size_t)col * 512 + ss * 8, wlds + col * 1024);
        }
    }
    __syncthreads();

    const int row0 = stile * 64 + wave * 16;
    const float* xrow = Xp + ((size_t)b * S + row0 + c) * D;
    const f32x4 zero = {0.f, 0.f, 0.f, 0.f};
    f32x4 acc[4] = {zero, zero, zero, zero};

    for (int k0 = 0; k0 < D; k0 += 32) {
        bf16x8 a;
        const float4 f0 = *reinterpret_cast<const float4*>(xrow + k0 + g * 8);
        const float4 f1 = *reinterpret_cast<const float4*>(xrow + k0 + g * 8 + 4);
        a[0] = (bf16_t)f0.x; a[1] = (bf16_t)f0.y; a[2] = (bf16_t)f0.z; a[3] = (bf16_t)f0.w;
        a[4] = (bf16_t)f1.x; a[5] = (bf16_t)f1.y; a[6] = (bf16_t)f1.z; a[7] = (bf16_t)f1.w;
#pragma unroll
        for (int ct = 0; ct < 4; ++ct) {
            const int col = ct * 16 + c;
            const bf16x8 wf = *reinterpret_cast<const bf16x8*>(
                wlds + col * 1024 + ((k0 * 2 + g * 16) ^ ((col & 7) << 4)));
            acc[ct] = __builtin_amdgcn_mfma_f32_16x16x32_bf16(a, wf, acc[ct], 0, 0, 0);
        }
    }

#pragma unroll
    for (int ct = 0; ct < 4; ++ct) {
        const int col = ct * 16 + c;
        const float bval = bias[h * KD + col];
        if (mat < 2) {
            bf16_t* outp = (mat == 0 ? Qo : Ko);
#pragma unroll
            for (int i = 0; i < 4; ++i) {
                const int r = row0 + g * 4 + i;
                outp[((size_t)bh * S + r) * KD + col] = (bf16_t)((acc[ct][i] + bval) * scale);
            }
        } else {
            bf16x4 o;
#pragma unroll
            for (int i = 0; i < 4; ++i) o[i] = (bf16_t)(acc[ct][i] + bval);
            *reinterpret_cast<bf16x4*>(VTo + ((size_t)bh * KD + col) * S + row0 + 4 * g) = o;
        }
    }
}

// ---------------------------------------------------------------------------
// Kernel 2: flash attention, 32x32 MFMA. 512 blocks (2/CU) x 128 thr (2 waves
// x 32 q-rows). K rows placed in LDS with sigma = bit2<->bit3 swap so the
// QK^T D-layout registers ARE the PV B-fragments (kv order per lane-half:
// h=0 -> [0..7,16..23], h=1 -> [8..15,24..31], +32 per second score block).
// Lane-local softmax over 32 scores; defer-max; exp2 domain; P in-register.
// acc = ctx^T[d][q]; epilogue scatters bf16x4 chunks to ctx [B*S, 512].
// ---------------------------------------------------------------------------
__global__ __launch_bounds__(128) void attn_kernel(
    const bf16_t* __restrict__ Q,   // [BH, S, 64] (pre-scaled by 0.125*log2e)
    const bf16_t* __restrict__ Km,  // [BH, S, 64]
    const bf16_t* __restrict__ VT,  // [BH, 64, S]
    bf16_t* __restrict__ CTX)       // [B*S, 512] bf16
{
    __shared__ char kv_lds[2][16384];   // per buf: K [64][128B] | V [64][128B]

    // XCD-bijective swizzle: 2 bh per XCD, 32 stiles each.
    const int hw = blockIdx.x;                 // 0..511
    const int xcd = hw & 7, idx = hw >> 3;     // idx 0..63
    const int bh = xcd * 2 + (idx >> 5);
    const int stile = idx & 31;
    const int b = bh >> 3, hh = bh & (H - 1);

    const int tid = threadIdx.x, wave = tid >> 6, lane = tid & 63;
    const int q = lane & 31, lh = lane >> 5;
    const int q0w = stile * 64 + wave * 32;

    const bf16_t* kg = Km + (size_t)bh * S * KD;
    const bf16_t* vg = VT + (size_t)bh * KD * S;

    // Q B-fragments (col = q, k-slice = ks*16 + lh*8 + j), loaded once
    bf16x8 qf[4];
    {
        const bf16_t* qp = Q + ((size_t)bh * S + q0w + q) * KD + lh * 8;
#pragma unroll
        for (int ks = 0; ks < 4; ++ks) qf[ks] = *reinterpret_cast<const bf16x8*>(qp + ks * 16);
    }

    // swizzled LDS read offsets (ys is identical for rows r and r+32)
    int koff[2][4], voff[2][4];
    {
        const int ysr = (q & 7) ^ (((q >> 3) & 1) << 2);
#pragma unroll
        for (int ks = 0; ks < 4; ++ks) {
            const int xo = (ks * 32 + lh * 16) ^ (ysr << 4);
            koff[0][ks] = q * 128 + xo;
            koff[1][ks] = (q + 32) * 128 + xo;
            voff[0][ks] = 8192 + q * 128 + xo;
            voff[1][ks] = 8192 + (q + 32) * 128 + xo;
        }
    }

    // staging geometry: wave0 -> K (sigma row permute), wave1 -> V (identity)
    int ksrc[8]; size_t vsrc[8];
    {
        const int sr = lane >> 3, sl = lane & 7;
#pragma unroll
        for (int j = 0; j < 8; ++j) {
            const int a  = j * 8 + sr;
            const int sa = (a & ~12) | ((a & 4) << 1) | ((a & 8) >> 1);  // swap bits 2,3
            const int ys = (a & 7) ^ (((a >> 3) & 1) << 2);
            ksrc[j] = sa * KD + (sl ^ ys) * 8;
            vsrc[j] = (size_t)a * S + (sl ^ ys) * 8;
        }
    }

#define STAGE(bufidx, kv0)                                                     \
    do {                                                                       \
        char* bp = kv_lds[bufidx];                                             \
        if (wave == 0) {                                                       \
            _Pragma("unroll") for (int j = 0; j < 8; ++j)                      \
                async_copy16(kg + (size_t)(kv0) * KD + ksrc[j], bp + j * 1024);\
        } else {                                                               \
            _Pragma("unroll") for (int j = 0; j < 8; ++j)                      \
                async_copy16(vg + vsrc[j] + (kv0), bp + 8192 + j * 1024);      \
        }                                                                      \
    } while (0)

    f32x16 o0 = {0.f}, o1 = {0.f};
    float m_run = -1e30f, l_run = 0.f;

    STAGE(0, 0);
    __syncthreads();

    int buf = 0;
    for (int t = 0; t < S / 64; ++t) {
        if (t < S / 64 - 1) STAGE(buf ^ 1, (t + 1) * 64);
        const char* kb = kv_lds[buf];

        // ---- QK^T: sc0 = rows 0..31 (kv via sigma), sc1 = rows 32..63
        f32x16 sc0 = {0.f}, sc1 = {0.f};
        __builtin_amdgcn_s_setprio(1);
#pragma unroll
        for (int ks = 0; ks < 4; ++ks) {
            const bf16x8 k0 = *reinterpret_cast<const bf16x8*>(kb + koff[0][ks]);
            sc0 = __builtin_amdgcn_mfma_f32_32x32x16_bf16(k0, qf[ks], sc0, 0, 0, 0);
            const bf16x8 k1 = *reinterpret_cast<const bf16x8*>(kb + koff[1][ks]);
            sc1 = __builtin_amdgcn_mfma_f32_32x32x16_bf16(k1, qf[ks], sc1, 0, 0, 0);
        }
        __builtin_amdgcn_s_setprio(0);

        // ---- softmax (lane-local; defer-max, exp2 domain)
        float pm = fmaxf(sc0[0], sc1[0]);
#pragma unroll
        for (int j = 1; j < 16; ++j) pm = fmaxf(pm, fmaxf(sc0[j], sc1[j]));
        if (!__all(pm <= m_run + 8.0f)) {
            pm = fmaxf(pm, __shfl_xor(pm, 32));
            const float mn = fmaxf(m_run, pm);
            const float fs = exp2f(m_run - mn);
            m_run = mn;
            l_run *= fs;
            o0 *= fs; o1 *= fs;
        }

        bf16x8 pf0, pf1, pf2, pf3;
        float ls = 0.f;
#pragma unroll
        for (int j = 0; j < 8; ++j) {
            const float e0 = exp2f(sc0[j]     - m_run);
            const float e1 = exp2f(sc0[8 + j] - m_run);
            const float e2 = exp2f(sc1[j]     - m_run);
            const float e3 = exp2f(sc1[8 + j] - m_run);
            pf0[j] = (bf16_t)e0; pf1[j] = (bf16_t)e1;
            pf2[j] = (bf16_t)e2; pf3[j] = (bf16_t)e3;
            ls += (e0 + e1) + (e2 + e3);
        }
        l_run += ls;

        // ---- PV: o[dg] += V-frag(kv-slice m) x P-frag(m)
        __builtin_amdgcn_s_setprio(1);
        {
            const bf16x8 v00 = *reinterpret_cast<const bf16x8*>(kb + voff[0][0]);
            const bf16x8 v10 = *reinterpret_cast<const bf16x8*>(kb + voff[1][0]);
            o0 = __builtin_amdgcn_mfma_f32_32x32x16_bf16(v00, pf0, o0, 0, 0, 0);
            o1 = __builtin_amdgcn_mfma_f32_32x32x16_bf16(v10, pf0, o1, 0, 0, 0);
            const bf16x8 v01 = *reinterpret_cast<const bf16x8*>(kb + voff[0][1]);
            const bf16x8 v11 = *reinterpret_cast<const bf16x8*>(kb + voff[1][1]);
            o0 = __builtin_amdgcn_mfma_f32_32x32x16_bf16(v01, pf1, o0, 0, 0, 0);
            o1 = __builtin_amdgcn_mfma_f32_32x32x16_bf16(v11, pf1, o1, 0, 0, 0);
            const bf16x8 v02 = *reinterpret_cast<const bf16x8*>(kb + voff[0][2]);
            const bf16x8 v12 = *reinterpret_cast<const bf16x8*>(kb + voff[1][2]);
            o0 = __builtin_amdgcn_mfma_f32_32x32x16_bf16(v02, pf2, o0, 0, 0, 0);
            o1 = __builtin_amdgcn_mfma_f32_32x32x16_bf16(v12, pf2, o1, 0, 0, 0);
            const bf16x8 v03 = *reinterpret_cast<const bf16x8*>(kb + voff[0][3]);
            const bf16x8 v13 = *reinterpret_cast<const bf16x8*>(kb + voff[1][3]);
            o0 = __builtin_amdgcn_mfma_f32_32x32x16_bf16(v03, pf3, o0, 0, 0, 0);
            o1 = __builtin_amdgcn_mfma_f32_32x32x16_bf16(v13, pf3, o1, 0, 0, 0);
        }
        __builtin_amdgcn_s_setprio(0);

        __syncthreads();
        buf ^= 1;
    }
#undef STAGE

    // ---- finalize: pair-sum l, normalize, scatter bf16x4 chunks
    l_run += __shfl_xor(l_run, 32);
    const float inv = 1.0f / l_run;

    bf16_t* crow = CTX + ((size_t)b * S + q0w + q) * 512 + hh * 64;
#pragma unroll
    for (int dg = 0; dg < 2; ++dg) {
        const f32x16& o = dg ? o1 : o0;
#pragma unroll
        for (int quad = 0; quad < 4; ++quad) {
            const int d0 = dg * 32 + quad * 8 + lh * 4;
            bf16x4 ov;
#pragma unroll
            for (int i = 0; i < 4; ++i) ov[i] = (bf16_t)(o[quad * 4 + i] * inv);
            *reinterpret_cast<bf16x4*>(crow + d0) = ov;
        }
    }
}

// ---------------------------------------------------------------------------
// Kernel 3: output projection. out = CTX[4096x512](bf16) @ WoT^T + bo.
// grid = 64 m x 8 n = 512 blocks, 256 thr (4 waves x 16 rows).
// ---------------------------------------------------------------------------
__global__ __launch_bounds__(256) void out_proj_kernel(
    const bf16_t* __restrict__ CTX,
    const bf16_t* __restrict__ WoT,   // [512 n][512 k]
    const float* __restrict__ bo,
    float* __restrict__ out)
{
    const int ntile = blockIdx.x & 7;
    const int mtile = blockIdx.x >> 3;
    const int n0 = ntile * 64;

    const int tid = threadIdx.x, wave = tid >> 6, lane = tid & 63;
    const int g = lane >> 4, c = lane & 15;
    const int row0 = mtile * 64 + wave * 16;

    const f32x4 zero = {0.f, 0.f, 0.f, 0.f};
    f32x4 acc[4] = {zero, zero, zero, zero};

    const bf16_t* arow = CTX + (size_t)(row0 + c) * 512;
    for (int ks = 0; ks < 16; ++ks) {
        const bf16x8 a = *reinterpret_cast<const bf16x8*>(arow + ks * 32 + g * 8);
#pragma unroll
        for (int ct = 0; ct < 4; ++ct) {
            const bf16x8 wf = *reinterpret_cast<const bf16x8*>(
                WoT + (size_t)(n0 + ct * 16 + c) * 512 + ks * 32 + g * 8);
            acc[ct] = __builtin_amdgcn_mfma_f32_16x16x32_bf16(a, wf, acc[ct], 0, 0, 0);
        }
    }

#pragma unroll
    for (int ct = 0; ct < 4; ++ct) {
        const int col = n0 + ct * 16 + c;
        const float bval = bo[col];
#pragma unroll
        for (int i = 0; i < 4; ++i)
            out[(size_t)(row0 + 4 * g + i) * 512 + col] = acc[ct][i] + bval;
    }
}

// ---------------------------------------------------------------------------
extern "C" void kernel_launch(void* const* d_in, const int* in_sizes, int n_in,
                              void* d_out, int out_size, void* d_ws, size_t ws_size,
                              hipStream_t stream) {
    const float* query = (const float*)d_in[0];
    const float* key_  = (const float*)d_in[1];
    const float* value = (const float*)d_in[2];
    const float* Wq = (const float*)d_in[3];
    const float* bq = (const float*)d_in[4];
    const float* Wk = (const float*)d_in[5];
    const float* bk = (const float*)d_in[6];
    const float* Wv = (const float*)d_in[7];
    const float* bv = (const float*)d_in[8];
    const float* Wo = (const float*)d_in[9];
    const float* bo = (const float*)d_in[10];

    char* wsb = (char*)d_ws;
    bf16_t* Qw   = (bf16_t*)(wsb);                     // 4 MB
    bf16_t* Kw   = (bf16_t*)(wsb + (4u  << 20));       // 4 MB
    bf16_t* VTw  = (bf16_t*)(wsb + (8u  << 20));       // 4 MB
    bf16_t* CTXb = (bf16_t*)(wsb + (12u << 20));       // 4 MB (aliases Wt* after qkv)
    bf16_t* Wtq  = (bf16_t*)(wsb + (12u << 20));       // 512 KB (dead after qkv)
    bf16_t* Wtk  = Wtq + 8 * 64 * 512;                 // 512 KB
    bf16_t* Wtv  = Wtk + 8 * 64 * 512;                 // 512 KB
    bf16_t* WoTw = (bf16_t*)(wsb + (16u << 20));       // 512 KB  (total 16.5 MB)

    prep_kernel<<<256, 256, 0, stream>>>(Wq, Wk, Wv, Wo, Wtq, Wtk, Wtv, WoTw);
    qkv_kernel<<<dim3(512, 3), 256, 0, stream>>>(query, key_, value,
                                                 Wtq, Wtk, Wtv, bq, bk, bv,
                                                 Qw, Kw, VTw);
    attn_kernel<<<512, 128, 0, stream>>>(Qw, Kw, VTw, CTXb);
    out_proj_kernel<<<512, 256, 0, stream>>>(CTXb, WoTw, bo, (float*)d_out);
}

// Round 5
// 102.979 us; speedup vs baseline: 1.2346x; 1.2346x over previous
//
#include <hip/hip_runtime.h>

#define B 2
#define S 2048
#define D 512
#define H 8
#define KD 64

typedef __bf16 bf16_t;
typedef __bf16 bf16x8 __attribute__((ext_vector_type(8)));
typedef __bf16 bf16x4 __attribute__((ext_vector_type(4)));
typedef float f32x4 __attribute__((ext_vector_type(4)));

#define QSCALE 0.1803368801111204f   /* 0.125 * log2(e): exp2-domain softmax */

__device__ __forceinline__ void async_copy16(const void* g, void* l) {
    __builtin_amdgcn_global_load_lds(
        (const __attribute__((address_space(1))) void*)g,
        (__attribute__((address_space(3))) void*)l, 16, 0, 0);
}

// ---------------------------------------------------------------------------
// Kernel 0: weight prep (transpose + f32->bf16, once per launch):
//   Wt{q,k,v}[h][col(64)][d(512)]  <-  W*[h][d][col]
//   WoT[n(512)][k(512)]            <-  Wo[k][n]
// ---------------------------------------------------------------------------
__global__ __launch_bounds__(256) void prep_kernel(
    const float* __restrict__ Wq, const float* __restrict__ Wk,
    const float* __restrict__ Wv, const float* __restrict__ Wo,
    bf16_t* __restrict__ Wtq, bf16_t* __restrict__ Wtk,
    bf16_t* __restrict__ Wtv, bf16_t* __restrict__ WoT)
{
    __shared__ bf16_t tl[64][72];
    const int blk = blockIdx.x, t = threadIdx.x;

    const float* src; bf16_t* dstbase;
    int ld, r0, c0;
    if (blk < 192) {                       // Wq/Wk/Wv
        const int mat = blk >> 6, h = (blk & 63) >> 3, dt = blk & 7;
        const float* W = (mat == 0) ? Wq : (mat == 1) ? Wk : Wv;
        bf16_t* Wt = (mat == 0) ? Wtq : (mat == 1) ? Wtk : Wtv;
        src = W + (size_t)h * D * KD; dstbase = Wt + (size_t)h * KD * D;
        ld = KD; r0 = dt * 64; c0 = 0;
    } else {                               // Wo
        const int kt = (blk - 192) >> 3, nt = (blk - 192) & 7;
        src = Wo; dstbase = WoT;
        ld = D; r0 = kt * 64; c0 = nt * 64;
    }

    { // phase 1: read f32 rows, convert, store to LDS [row][col]
        const int r = t >> 2, cq = (t & 3) * 16;
        const float* sp = src + (size_t)(r0 + r) * ld + c0 + cq;
#pragma unroll
        for (int q = 0; q < 4; ++q) {
            const float4 f = *reinterpret_cast<const float4*>(sp + q * 4);
            tl[r][cq + q * 4 + 0] = (bf16_t)f.x; tl[r][cq + q * 4 + 1] = (bf16_t)f.y;
            tl[r][cq + q * 4 + 2] = (bf16_t)f.z; tl[r][cq + q * 4 + 3] = (bf16_t)f.w;
        }
    }
    __syncthreads();
    { // phase 2: gather transposed, 16B stores
        const int cc = t >> 2, rq = (t & 3) * 16;
        bf16x8 o0, o1;
#pragma unroll
        for (int j = 0; j < 8; ++j) { o0[j] = tl[rq + j][cc]; o1[j] = tl[rq + 8 + j][cc]; }
        bf16_t* dp = dstbase + (size_t)(c0 + cc) * 512 + r0 + rq;
        *reinterpret_cast<bf16x8*>(dp) = o0;
        *reinterpret_cast<bf16x8*>(dp + 8) = o1;
    }
}

// ---------------------------------------------------------------------------
// Kernel 1: fused QKV projection (R3 version — measured good).
// ---------------------------------------------------------------------------
__global__ __launch_bounds__(256) void qkv_kernel(
    const float* __restrict__ q_in, const float* __restrict__ k_in, const float* __restrict__ v_in,
    const bf16_t* __restrict__ Wtq, const bf16_t* __restrict__ Wtk, const bf16_t* __restrict__ Wtv,
    const float* __restrict__ bq, const float* __restrict__ bk, const float* __restrict__ bv,
    bf16_t* __restrict__ Qo, bf16_t* __restrict__ Ko, bf16_t* __restrict__ VTo)
{
    __shared__ char wlds[65536];

    const int mat = blockIdx.y;
    const float* Xp     = (mat == 0) ? q_in : (mat == 1) ? k_in : v_in;
    const bf16_t* Wt    = (mat == 0) ? Wtq  : (mat == 1) ? Wtk  : Wtv;
    const float* bias   = (mat == 0) ? bq   : (mat == 1) ? bk   : bv;
    const float scale   = (mat == 0) ? QSCALE : 1.0f;

    const int stile = blockIdx.x & 31;
    const int bh    = blockIdx.x >> 5;
    const int h = bh & (H - 1), b = bh >> 3;

    const int tid = threadIdx.x, wave = tid >> 6, lane = tid & 63;
    const int g = lane >> 4, c = lane & 15;

    // stage Wt[h]: LDS[col][slot] = W[col][slot ^ (col&7)]  (64 x 1KB rows)
    {
        const bf16_t* wbase = Wt + (size_t)h * (64 * 512);
#pragma unroll
        for (int j = 0; j < 16; ++j) {
            const int col = wave * 16 + j;
            const int ss = lane ^ (col & 7);
            async_copy16(wbase + (size_t)col * 512 + ss * 8, wlds + col * 1024);
        }
    }
    __syncthreads();

    const int row0 = stile * 64 + wave * 16;
    const float* xrow = Xp + ((size_t)b * S + row0 + c) * D;
    const f32x4 zero = {0.f, 0.f, 0.f, 0.f};
    f32x4 acc[4] = {zero, zero, zero, zero};

    for (int k0 = 0; k0 < D; k0 += 32) {
        bf16x8 a;
        const float4 f0 = *reinterpret_cast<const float4*>(xrow + k0 + g * 8);
        const float4 f1 = *reinterpret_cast<const float4*>(xrow + k0 + g * 8 + 4);
        a[0] = (bf16_t)f0.x; a[1] = (bf16_t)f0.y; a[2] = (bf16_t)f0.z; a[3] = (bf16_t)f0.w;
        a[4] = (bf16_t)f1.x; a[5] = (bf16_t)f1.y; a[6] = (bf16_t)f1.z; a[7] = (bf16_t)f1.w;
#pragma unroll
        for (int ct = 0; ct < 4; ++ct) {
            const int col = ct * 16 + c;
            const bf16x8 wf = *reinterpret_cast<const bf16x8*>(
                wlds + col * 1024 + ((k0 * 2 + g * 16) ^ ((col & 7) << 4)));
            acc[ct] = __builtin_amdgcn_mfma_f32_16x16x32_bf16(a, wf, acc[ct], 0, 0, 0);
        }
    }

#pragma unroll
    for (int ct = 0; ct < 4; ++ct) {
        const int col = ct * 16 + c;
        const float bval = bias[h * KD + col];
        if (mat < 2) {
            bf16_t* outp = (mat == 0 ? Qo : Ko);
#pragma unroll
            for (int i = 0; i < 4; ++i) {
                const int r = row0 + g * 4 + i;
                outp[((size_t)bh * S + r) * KD + col] = (bf16_t)((acc[ct][i] + bval) * scale);
            }
        } else {
            bf16x4 o;
#pragma unroll
            for (int i = 0; i < 4; ++i) o[i] = (bf16_t)(acc[ct][i] + bval);
            *reinterpret_cast<bf16x4*>(VTo + ((size_t)bh * KD + col) * S + row0 + 4 * g) = o;
        }
    }
}

// ---------------------------------------------------------------------------
// Kernel 2: flash attention, R3 main loop + KV-split over grid (flash-decode).
// 256*SPLIT blocks (XCD-pinned per bh), 512 thr (8 waves x 16 q-rows).
// Each block handles a 128-row Q tile against an S/SPLIT KV chunk, emitting
// either final ctx (SPLIT==1) or partial {m, l, O[64]} per q-row.
// ---------------------------------------------------------------------------
template <int SPLIT>
__global__ __launch_bounds__(512) void attn_kernel(
    const bf16_t* __restrict__ Q,   // [BH, S, 64] (pre-scaled)
    const bf16_t* __restrict__ Km,  // [BH, S, 64]
    const bf16_t* __restrict__ VT,  // [BH, 64, S]
    bf16_t* __restrict__ CTX,       // [B*S, 512] bf16 (SPLIT==1)
    float* __restrict__ Opart,      // [SPLIT][16][2048][64] f32 (SPLIT>1)
    float* __restrict__ ML)         // [SPLIT][16][2048][2]  f32 (SPLIT>1)
{
    __shared__ char kv_lds[2][16384];   // per buf: K [64][128B] | V [64][128B]

    // XCD-bijective: all chunks & q-tiles of a bh stay on one XCD.
    const int hw = blockIdx.x;                       // 256*SPLIT blocks
    const int xcd = hw & 7;
    const int idx = hw >> 3;                         // 0 .. 32*SPLIT-1
    const int bh = xcd * 2 + (idx >= 16 * SPLIT ? 1 : 0);
    const int r2 = idx & (16 * SPLIT - 1);
    const int chunk = r2 >> 4;
    const int stile = r2 & 15;
    const int b = bh >> 3, h = bh & (H - 1);

    const int tid = threadIdx.x, wave = tid >> 6, lane = tid & 63;
    const int g = lane >> 4, c = lane & 15;
    const int q0 = stile * 128 + wave * 16;
    const int kvbeg = chunk * (S / SPLIT);
    const int NT = (S / SPLIT) / 64;

    const bf16_t* kg = Km + (size_t)bh * S * KD;
    const bf16_t* vg = VT + (size_t)bh * KD * S;

    // Q fragments (B-operand; col = q-row = c)
    const bf16_t* qp = Q + ((size_t)bh * S + q0 + c) * KD;
    const bf16x8 qlo = *reinterpret_cast<const bf16x8*>(qp + g * 8);
    const bf16x8 qhi = *reinterpret_cast<const bf16x8*>(qp + 32 + g * 8);

    // hoisted swizzled LDS read offsets
    int koff[4][2], voff[4][2];
#pragma unroll
    for (int tt = 0; tt < 4; ++tt) {
        const int row = 8 * (c >> 2) + (c & 3) + 4 * (tt & 1) + 32 * (tt >> 1);
        const int ys = (row & 7) ^ (((row >> 3) & 1) << 2);
        koff[tt][0] = row * 128 + ((g * 16) ^ (ys << 4));
        koff[tt][1] = row * 128 + ((64 + g * 16) ^ (ys << 4));
    }
#pragma unroll
    for (int ct = 0; ct < 4; ++ct) {
        const int row = ct * 16 + c;
        const int ys = (row & 7) ^ (((row >> 3) & 1) << 2);
        voff[ct][0] = 8192 + row * 128 + ((g * 16) ^ (ys << 4));
        voff[ct][1] = 8192 + row * 128 + ((64 + g * 16) ^ (ys << 4));
    }

    // staging lane geometry
    const int srow = lane >> 3, sslot = lane & 7;
    const int kwv = wave & 3;
    const int krow0a = kwv * 16, krow0b = kwv * 16 + 8;
    const int rowa = krow0a + srow, rowb = krow0b + srow;
    const int ysa = (rowa & 7) ^ (((rowa >> 3) & 1) << 2);
    const int ysb = (rowb & 7) ^ (((rowb >> 3) & 1) << 2);
    const int ssa = sslot ^ ysa, ssb = sslot ^ ysb;

    const f32x4 zero = {0.f, 0.f, 0.f, 0.f};
    f32x4 acc[4] = {zero, zero, zero, zero};
    float m_run = -1e30f, l_run = 0.f;

#define STAGE(bufidx, kv0)                                                        \
    do {                                                                          \
        char* bp = kv_lds[0] + (bufidx) * 16384;                                  \
        if (wave < 4) {                                                           \
            async_copy16(kg + (size_t)((kv0) + rowa) * KD + ssa * 8, bp + krow0a * 128); \
            async_copy16(kg + (size_t)((kv0) + rowb) * KD + ssb * 8, bp + krow0b * 128); \
        } else {                                                                  \
            async_copy16(vg + (size_t)rowa * S + (kv0) + ssa * 8, bp + 8192 + krow0a * 128); \
            async_copy16(vg + (size_t)rowb * S + (kv0) + ssb * 8, bp + 8192 + krow0b * 128); \
        }                                                                         \
    } while (0)

    STAGE(0, kvbeg);
    __syncthreads();

    int buf = 0;
    for (int t = 0; t < NT; ++t) {
        if (t < NT - 1) STAGE(buf ^ 1, kvbeg + (t + 1) * 64);
        const char* kb = kv_lds[0] + buf * 16384;

        // ---- QK^T (swapped)
        f32x4 sc[4];
        __builtin_amdgcn_s_setprio(1);
#pragma unroll
        for (int tt = 0; tt < 4; ++tt) {
            const bf16x8 k0f = *reinterpret_cast<const bf16x8*>(kb + koff[tt][0]);
            const bf16x8 k1f = *reinterpret_cast<const bf16x8*>(kb + koff[tt][1]);
            f32x4 z = zero;
            z = __builtin_amdgcn_mfma_f32_16x16x32_bf16(k0f, qlo, z, 0, 0, 0);
            sc[tt] = __builtin_amdgcn_mfma_f32_16x16x32_bf16(k1f, qhi, z, 0, 0, 0);
        }
        __builtin_amdgcn_s_setprio(0);

        // ---- softmax (exp2 domain, deferred max)
        const float a0 = fmaxf(fmaxf(sc[0][0], sc[0][1]), fmaxf(sc[0][2], sc[0][3]));
        const float a1 = fmaxf(fmaxf(sc[1][0], sc[1][1]), fmaxf(sc[1][2], sc[1][3]));
        const float a2 = fmaxf(fmaxf(sc[2][0], sc[2][1]), fmaxf(sc[2][2], sc[2][3]));
        const float a3 = fmaxf(fmaxf(sc[3][0], sc[3][1]), fmaxf(sc[3][2], sc[3][3]));
        float pm = fmaxf(fmaxf(a0, a1), fmaxf(a2, a3));
        if (!__all(pm <= m_run + 8.0f)) {
            pm = fmaxf(pm, __shfl_xor(pm, 16));
            pm = fmaxf(pm, __shfl_xor(pm, 32));
            const float mn = fmaxf(m_run, pm);
            const float fs = exp2f(m_run - mn);
            m_run = mn;
            l_run *= fs;
#pragma unroll
            for (int ct = 0; ct < 4; ++ct) acc[ct] = acc[ct] * fs;
        }

        bf16x8 f0, f1;
        float ls = 0.f;
#pragma unroll
        for (int i = 0; i < 4; ++i) {
            const float p0 = exp2f(sc[0][i] - m_run);
            const float p1 = exp2f(sc[1][i] - m_run);
            const float p2 = exp2f(sc[2][i] - m_run);
            const float p3 = exp2f(sc[3][i] - m_run);
            f0[i] = (bf16_t)p0; f0[4 + i] = (bf16_t)p1;
            f1[i] = (bf16_t)p2; f1[4 + i] = (bf16_t)p3;
            ls += (p0 + p1) + (p2 + p3);
        }
        l_run += ls;

        // ---- PV
        __builtin_amdgcn_s_setprio(1);
#pragma unroll
        for (int ct = 0; ct < 4; ++ct) {
            const bf16x8 v0f = *reinterpret_cast<const bf16x8*>(kb + voff[ct][0]);
            const bf16x8 v1f = *reinterpret_cast<const bf16x8*>(kb + voff[ct][1]);
            acc[ct] = __builtin_amdgcn_mfma_f32_16x16x32_bf16(v0f, f0, acc[ct], 0, 0, 0);
            acc[ct] = __builtin_amdgcn_mfma_f32_16x16x32_bf16(v1f, f1, acc[ct], 0, 0, 0);
        }
        __builtin_amdgcn_s_setprio(0);

        __syncthreads();
        buf ^= 1;
    }
#undef STAGE

    // fold l across the 4 g-copies of each q-row
    l_run += __shfl_xor(l_run, 16);
    l_run += __shfl_xor(l_run, 32);

    if constexpr (SPLIT == 1) {
        const float inv = 1.0f / l_run;
        bf16_t* crow = CTX + ((size_t)b * S + q0 + c) * 512 + h * 64;
#pragma unroll
        for (int ct = 0; ct < 4; ++ct) {
            bf16x4 o;
#pragma unroll
            for (int i = 0; i < 4; ++i) o[i] = (bf16_t)(acc[ct][i] * inv);
            *reinterpret_cast<bf16x4*>(crow + ct * 16 + 4 * g) = o;
        }
    } else {
        const size_t prow = (size_t)(chunk * 16 + bh) * 2048 + q0 + c;
        float* orow = Opart + prow * 64;
#pragma unroll
        for (int ct = 0; ct < 4; ++ct) {
            f32x4 o = acc[ct];
            *reinterpret_cast<f32x4*>(orow + ct * 16 + 4 * g) = o;
        }
        if (g == 0) {
            float2 ml; ml.x = m_run; ml.y = l_run;
            *reinterpret_cast<float2*>(ML + prow * 2) = ml;
        }
    }
}

// ---------------------------------------------------------------------------
// Kernel 2b: combine KV-split partials -> bf16 ctx. 2048 blocks x 256.
// thread -> (bh, s, d4): ctx = sum_i w_i*O_i / sum_i w_i*l_i, w_i = 2^(m_i-M).
// ---------------------------------------------------------------------------
template <int SPLIT>
__global__ __launch_bounds__(256) void combine_kernel(
    const float* __restrict__ Opart, const float* __restrict__ ML,
    bf16_t* __restrict__ CTX)
{
    const int gid = blockIdx.x * 256 + threadIdx.x;
    const int d4 = gid & 15, rowh = gid >> 4;       // rowh = bh*2048 + s
    const int bh = rowh >> 11, s = rowh & 2047;
    const int b = bh >> 3, h = bh & (H - 1);

    float m[SPLIT], l[SPLIT], M = -1e30f;
#pragma unroll
    for (int i = 0; i < SPLIT; ++i) {
        const float2 v = *reinterpret_cast<const float2*>(
            ML + ((size_t)(i * 16 + bh) * 2048 + s) * 2);
        m[i] = v.x; l[i] = v.y;
        M = fmaxf(M, m[i]);
    }
    f32x4 o = {0.f, 0.f, 0.f, 0.f};
    float wsum = 0.f;
#pragma unroll
    for (int i = 0; i < SPLIT; ++i) {
        const float w = exp2f(m[i] - M);
        wsum += w * l[i];
        const f32x4 ov = *reinterpret_cast<const f32x4*>(
            Opart + ((size_t)(i * 16 + bh) * 2048 + s) * 64 + d4 * 4);
        o += ov * w;
    }
    const float inv = 1.0f / wsum;
    bf16x4 r;
#pragma unroll
    for (int i = 0; i < 4; ++i) r[i] = (bf16_t)(o[i] * inv);
    *reinterpret_cast<bf16x4*>(CTX + ((size_t)b * S + s) * 512 + h * 64 + d4 * 4) = r;
}

// ---------------------------------------------------------------------------
// Kernel 3: output projection. out = CTX[4096x512](bf16) @ WoT^T + bo.
// ---------------------------------------------------------------------------
__global__ __launch_bounds__(256) void out_proj_kernel(
    const bf16_t* __restrict__ CTX,
    const bf16_t* __restrict__ WoT,   // [512 n][512 k]
    const float* __restrict__ bo,
    float* __restrict__ out)
{
    const int ntile = blockIdx.x & 7;
    const int mtile = blockIdx.x >> 3;
    const int n0 = ntile * 64;

    const int tid = threadIdx.x, wave = tid >> 6, lane = tid & 63;
    const int g = lane >> 4, c = lane & 15;
    const int row0 = mtile * 64 + wave * 16;

    const f32x4 zero = {0.f, 0.f, 0.f, 0.f};
    f32x4 acc[4] = {zero, zero, zero, zero};

    const bf16_t* arow = CTX + (size_t)(row0 + c) * 512;
    for (int ks = 0; ks < 16; ++ks) {
        const bf16x8 a = *reinterpret_cast<const bf16x8*>(arow + ks * 32 + g * 8);
#pragma unroll
        for (int ct = 0; ct < 4; ++ct) {
            const bf16x8 wf = *reinterpret_cast<const bf16x8*>(
                WoT + (size_t)(n0 + ct * 16 + c) * 512 + ks * 32 + g * 8);
            acc[ct] = __builtin_amdgcn_mfma_f32_16x16x32_bf16(a, wf, acc[ct], 0, 0, 0);
        }
    }

#pragma unroll
    for (int ct = 0; ct < 4; ++ct) {
        const int col = n0 + ct * 16 + c;
        const float bval = bo[col];
#pragma unroll
        for (int i = 0; i < 4; ++i)
            out[(size_t)(row0 + 4 * g + i) * 512 + col] = acc[ct][i] + bval;
    }
}

// ---------------------------------------------------------------------------
extern "C" void kernel_launch(void* const* d_in, const int* in_sizes, int n_in,
                              void* d_out, int out_size, void* d_ws, size_t ws_size,
                              hipStream_t stream) {
    const float* query = (const float*)d_in[0];
    const float* key_  = (const float*)d_in[1];
    const float* value = (const float*)d_in[2];
    const float* Wq = (const float*)d_in[3];
    const float* bq = (const float*)d_in[4];
    const float* Wk = (const float*)d_in[5];
    const float* bk = (const float*)d_in[6];
    const float* Wv = (const float*)d_in[7];
    const float* bv = (const float*)d_in[8];
    const float* Wo = (const float*)d_in[9];
    const float* bo = (const float*)d_in[10];

    char* wsb = (char*)d_ws;
    bf16_t* Qw   = (bf16_t*)(wsb);                       // 4 MB
    bf16_t* Kw   = (bf16_t*)(wsb + (4u  << 20));         // 4 MB
    bf16_t* VTw  = (bf16_t*)(wsb + (8u  << 20));         // 4 MB
    bf16_t* CTXb = (bf16_t*)(wsb + (12u << 20));         // 4 MB (Wt* alias inside)
    bf16_t* Wtq  = (bf16_t*)(wsb + (12u << 20));         // 512 KB (dead after qkv)
    bf16_t* Wtk  = Wtq + 8 * 64 * 512;
    bf16_t* Wtv  = Wtk + 8 * 64 * 512;
    bf16_t* WoTw = (bf16_t*)(wsb + (16u << 20));         // 512 KB
    float*  Opart = (float*)(wsb + (16u << 20) + (512u << 10));  // SPLIT x 8 MB
    // ML placed after the largest Opart actually used (computed below)

    const int SPLIT = (ws_size >= (50ull << 20)) ? 4
                    : (ws_size >= (34ull << 20)) ? 2 : 1;

    prep_kernel<<<256, 256, 0, stream>>>(Wq, Wk, Wv, Wo, Wtq, Wtk, Wtv, WoTw);
    qkv_kernel<<<dim3(512, 3), 256, 0, stream>>>(query, key_, value,
                                                 Wtq, Wtk, Wtv, bq, bk, bv,
                                                 Qw, Kw, VTw);

    if (SPLIT == 4) {
        float* MLp = Opart + 4ull * 16 * 2048 * 64;
        attn_kernel<4><<<1024, 512, 0, stream>>>(Qw, Kw, VTw, CTXb, Opart, MLp);
        combine_kernel<4><<<2048, 256, 0, stream>>>(Opart, MLp, CTXb);
    } else if (SPLIT == 2) {
        float* MLp = Opart + 2ull * 16 * 2048 * 64;
        attn_kernel<2><<<512, 512, 0, stream>>>(Qw, Kw, VTw, CTXb, Opart, MLp);
        combine_kernel<2><<<2048, 256, 0, stream>>>(Opart, MLp, CTXb);
    } else {
        attn_kernel<1><<<256, 512, 0, stream>>>(Qw, Kw, VTw, CTXb, nullptr, nullptr);
    }

    out_proj_kernel<<<512, 256, 0, stream>>>(CTXb, WoTw, bo, (float*)d_out);
}